// Round 1
// baseline (772.783 us; speedup 1.0000x reference)
//
#include <hip/hip_runtime.h>

// Problem constants
#define VSZ 32000
#define ESZ 1024
#define HSZ 1024
#define BSZ 64
#define SSZ 128

// ---------------------------------------------------------------------------
// Gather embedding rows into x[:, 0:1024]  (x is (64, 2048))
__global__ void k_gather(const int* __restrict__ idx, const float* __restrict__ emb,
                         float* __restrict__ x) {
    int b = blockIdx.x;
    int row = idx[b];
    const float4* src = (const float4*)(emb + (size_t)row * ESZ);
    float4* dst = (float4*)(x + (size_t)b * 2048);
    for (int i = threadIdx.x; i < ESZ / 4; i += blockDim.x) dst[i] = src[i];
}

// ---------------------------------------------------------------------------
// Generic skinny GEMM: C(64 x N) = A(64 x K) @ B(N x K)^T [+ bias] [+= if ACC]
// One block computes a 64x64 tile of C.  grid.x = N/64, block = 256.
template <int ACC>
__global__ __launch_bounds__(256) void k_gemm64(
    const float* __restrict__ A, int lda,
    const float* __restrict__ B, int ldb,
    const float* __restrict__ bias,
    float* __restrict__ C, int ldc, int K) {
    __shared__ float As[64][17];
    __shared__ float Bs[64][17];
    int t = threadIdx.x;
    int tx = t & 15, ty = t >> 4;
    int n0 = blockIdx.x * 64;
    int lr = t >> 2, lq = t & 3;
    float acc[4][4] = {};

    for (int k0 = 0; k0 < K; k0 += 16) {
        float4 av = *(const float4*)(A + (size_t)lr * lda + k0 + lq * 4);
        float4 bv = *(const float4*)(B + (size_t)(n0 + lr) * ldb + k0 + lq * 4);
        As[lr][lq * 4 + 0] = av.x; As[lr][lq * 4 + 1] = av.y;
        As[lr][lq * 4 + 2] = av.z; As[lr][lq * 4 + 3] = av.w;
        Bs[lr][lq * 4 + 0] = bv.x; Bs[lr][lq * 4 + 1] = bv.y;
        Bs[lr][lq * 4 + 2] = bv.z; Bs[lr][lq * 4 + 3] = bv.w;
        __syncthreads();
#pragma unroll
        for (int kk = 0; kk < 16; ++kk) {
            float a[4], bb[4];
#pragma unroll
            for (int i = 0; i < 4; ++i) a[i] = As[ty * 4 + i][kk];
#pragma unroll
            for (int j = 0; j < 4; ++j) bb[j] = Bs[tx * 4 + j][kk];
#pragma unroll
            for (int i = 0; i < 4; ++i)
#pragma unroll
                for (int j = 0; j < 4; ++j) acc[i][j] += a[i] * bb[j];
        }
        __syncthreads();
    }

#pragma unroll
    for (int i = 0; i < 4; ++i) {
        int r = ty * 4 + i;
#pragma unroll
        for (int j = 0; j < 4; ++j) {
            int c = n0 + tx * 4 + j;
            float v = acc[i][j];
            if (ACC) {
                C[(size_t)r * ldc + c] += v;
            } else {
                if (bias) v += bias[c];
                C[(size_t)r * ldc + c] = v;
            }
        }
    }
}

// ---------------------------------------------------------------------------
// Attention score GEMM with fused epilogue.
// kp_tile = enc(8192 x 1024) @ Ua^T tile; then
// scores[r] += sum_h Va[h] * tanh(kp[r][h] + qp[b][h] + Ua_b[h])
// grid = (16 h-tiles, 128 row-tiles), block = 256.  scores pre-zeroed.
__global__ __launch_bounds__(256) void k_attn_scores(
    const float* __restrict__ enc, const float* __restrict__ Ua,
    const float* __restrict__ Ua_b, const float* __restrict__ qp,
    const float* __restrict__ Va, float* __restrict__ scores) {
    __shared__ float As[64][17];
    __shared__ float Bs[64][17];
    __shared__ float red[64][17];
    int t = threadIdx.x;
    int tx = t & 15, ty = t >> 4;
    int h0 = blockIdx.x * 64;
    int r0 = blockIdx.y * 64;
    int lr = t >> 2, lq = t & 3;
    float acc[4][4] = {};

    for (int k0 = 0; k0 < 1024; k0 += 16) {
        float4 av = *(const float4*)(enc + (size_t)(r0 + lr) * 1024 + k0 + lq * 4);
        float4 bv = *(const float4*)(Ua + (size_t)(h0 + lr) * 1024 + k0 + lq * 4);
        As[lr][lq * 4 + 0] = av.x; As[lr][lq * 4 + 1] = av.y;
        As[lr][lq * 4 + 2] = av.z; As[lr][lq * 4 + 3] = av.w;
        Bs[lr][lq * 4 + 0] = bv.x; Bs[lr][lq * 4 + 1] = bv.y;
        Bs[lr][lq * 4 + 2] = bv.z; Bs[lr][lq * 4 + 3] = bv.w;
        __syncthreads();
#pragma unroll
        for (int kk = 0; kk < 16; ++kk) {
            float a[4], bb[4];
#pragma unroll
            for (int i = 0; i < 4; ++i) a[i] = As[ty * 4 + i][kk];
#pragma unroll
            for (int j = 0; j < 4; ++j) bb[j] = Bs[tx * 4 + j][kk];
#pragma unroll
            for (int i = 0; i < 4; ++i)
#pragma unroll
                for (int j = 0; j < 4; ++j) acc[i][j] += a[i] * bb[j];
        }
        __syncthreads();
    }

    // epilogue: tanh + weighted reduce over h within this tile
    int b = r0 >> 7;  // 64-row tile lies within a single batch b
#pragma unroll
    for (int i = 0; i < 4; ++i) {
        float sp = 0.f;
#pragma unroll
        for (int j = 0; j < 4; ++j) {
            int h = h0 + tx * 4 + j;
            float v = tanhf(acc[i][j] + qp[b * 1024 + h] + Ua_b[h]);
            sp += Va[h] * v;
        }
        red[ty * 4 + i][tx] = sp;
    }
    __syncthreads();
    if (t < 64) {
        float s = 0.f;
#pragma unroll
        for (int q = 0; q < 16; ++q) s += red[t][q];
        atomicAdd(scores + r0 + t, s);
    }
}

// ---------------------------------------------------------------------------
// Softmax over S=128 per batch; writes weights straight to d_out region.
__global__ void k_softmax(const float* __restrict__ scores, float* __restrict__ wout) {
    int b = blockIdx.x;
    int s = threadIdx.x;  // 128 threads
    __shared__ float buf[128];
    float v = scores[b * 128 + s];
    buf[s] = v;
    __syncthreads();
    for (int off = 64; off > 0; off >>= 1) {
        if (s < off) buf[s] = fmaxf(buf[s], buf[s + off]);
        __syncthreads();
    }
    float m = buf[0];
    __syncthreads();
    float e = expf(v - m);
    buf[s] = e;
    __syncthreads();
    for (int off = 64; off > 0; off >>= 1) {
        if (s < off) buf[s] += buf[s + off];
        __syncthreads();
    }
    float sum = buf[0];
    wout[b * 128 + s] = e / sum;
}

// ---------------------------------------------------------------------------
// context[b,h] = sum_s w[b,s] * enc[b,s,h]; writes into x[:, 1024:2048]
__global__ void k_context(const float* __restrict__ enc, const float* __restrict__ w,
                          float* __restrict__ x) {
    int b = blockIdx.x;
    int t = threadIdx.x;  // 256
    __shared__ float ws[128];
    if (t < 128) ws[t] = w[b * 128 + t];
    __syncthreads();
    float acc[4] = {0.f, 0.f, 0.f, 0.f};
    for (int s = 0; s < 128; ++s) {
        float wv = ws[s];
        const float* row = enc + ((size_t)b * 128 + s) * 1024;
#pragma unroll
        for (int j = 0; j < 4; ++j) acc[j] += wv * row[t + 256 * j];
    }
#pragma unroll
    for (int j = 0; j < 4; ++j) x[(size_t)b * 2048 + 1024 + t + 256 * j] = acc[j];
}

// ---------------------------------------------------------------------------
// LSTM pointwise. gates (64,4096) order [i|f|g|o]; adds biases here.
__global__ void k_lstm(const float* __restrict__ gates, const float* __restrict__ c0,
                       const float* __restrict__ b_ih, const float* __restrict__ b_hh,
                       float* __restrict__ h1, float* __restrict__ c1) {
    int idx = blockIdx.x * blockDim.x + threadIdx.x;  // 65536
    int b = idx >> 10, h = idx & 1023;
    const float* g = gates + (size_t)b * 4096;
    float iv = g[h] + b_ih[h] + b_hh[h];
    float fv = g[1024 + h] + b_ih[1024 + h] + b_hh[1024 + h];
    float gv = g[2048 + h] + b_ih[2048 + h] + b_hh[2048 + h];
    float ov = g[3072 + h] + b_ih[3072 + h] + b_hh[3072 + h];
    float si = 1.f / (1.f + expf(-iv));
    float sf = 1.f / (1.f + expf(-fv));
    float so = 1.f / (1.f + expf(-ov));
    float tg = tanhf(gv);
    float cc = sf * c0[idx] + si * tg;
    float hh = so * tanhf(cc);
    c1[idx] = cc;
    h1[idx] = hh;
}

// ---------------------------------------------------------------------------
extern "C" void kernel_launch(void* const* d_in, const int* in_sizes, int n_in,
                              void* d_out, int out_size, void* d_ws, size_t ws_size,
                              hipStream_t stream) {
    const int* idx = (const int*)d_in[0];
    const float* hidden = (const float*)d_in[1];   // (1,64,1024)
    const float* cell = (const float*)d_in[2];     // (1,64,1024)
    const float* enc = (const float*)d_in[3];      // (64,128,1024)
    const float* emb = (const float*)d_in[4];      // (32000,1024)
    const float* Wa_w = (const float*)d_in[5];     // (1024,1024)
    const float* Wa_b = (const float*)d_in[6];
    const float* Ua_w = (const float*)d_in[7];     // (1024,1024)
    const float* Ua_b = (const float*)d_in[8];
    const float* Va_w = (const float*)d_in[9];     // (1,1024)
    // d_in[10] Va_b: softmax is shift-invariant -> unused
    const float* W_ih = (const float*)d_in[11];    // (4096,2048)
    const float* W_hh = (const float*)d_in[12];    // (4096,1024)
    const float* b_ih = (const float*)d_in[13];
    const float* b_hh = (const float*)d_in[14];
    const float* out_w = (const float*)d_in[15];   // (32000,1024)
    const float* out_b = (const float*)d_in[16];

    float* out = (float*)d_out;
    float* logits = out;                               // 64*32000
    float* h1 = out + 2048000;                         // 64*1024
    float* c1 = out + 2048000 + 65536;                 // 64*1024
    float* wts = out + 2048000 + 65536 + 65536;        // 64*128

    float* ws = (float*)d_ws;
    float* qp = ws;                  // 65536
    float* scores = ws + 65536;      // 8192
    float* x = ws + 65536 + 8192;    // 64*2048 = 131072
    float* gates = x + 131072;       // 64*4096 = 262144

    hipMemsetAsync(scores, 0, 8192 * sizeof(float), stream);
    k_gather<<<64, 256, 0, stream>>>(idx, emb, x);
    // q_proj = h0 @ Wa^T + Wa_b
    k_gemm64<0><<<dim3(1024 / 64), 256, 0, stream>>>(hidden, 1024, Wa_w, 1024, Wa_b, qp, 1024, 1024);
    // scores (fused k_proj GEMM + tanh + Va reduce)
    k_attn_scores<<<dim3(16, 128), 256, 0, stream>>>(enc, Ua_w, Ua_b, qp, Va_w, scores);
    k_softmax<<<64, 128, 0, stream>>>(scores, wts);
    k_context<<<64, 256, 0, stream>>>(enc, wts, x);
    // gates = x @ W_ih^T ; gates += h0 @ W_hh^T  (biases added in k_lstm)
    k_gemm64<0><<<dim3(4096 / 64), 256, 0, stream>>>(x, 2048, W_ih, 2048, nullptr, gates, 4096, 2048);
    k_gemm64<1><<<dim3(4096 / 64), 256, 0, stream>>>(hidden, 1024, W_hh, 1024, nullptr, gates, 4096, 1024);
    k_lstm<<<256, 256, 0, stream>>>(gates, cell, b_ih, b_hh, h1, c1);
    // logits = h1 @ out_w^T + out_b
    k_gemm64<0><<<dim3(32000 / 64), 256, 0, stream>>>(h1, 1024, out_w, 1024, out_b, logits, 32000, 1024);
}

// Round 2
// 239.105 us; speedup vs baseline: 3.2320x; 3.2320x over previous
//
#include <hip/hip_runtime.h>

#define BSZ 64
#define SSZ 128

using short8 = __attribute__((ext_vector_type(8))) short;
using f32x4  = __attribute__((ext_vector_type(4))) float;

// f32 -> bf16 (RNE), pure integer ops
__device__ inline short f2b(float f) {
    unsigned u = __float_as_uint(f);
    unsigned r = (u + 0x7FFFu + ((u >> 16) & 1u)) >> 16;
    return (short)r;
}

// load 8 consecutive f32, convert to 8 bf16
__device__ inline short8 ld8(const float* __restrict__ g) {
    float4 v0 = *(const float4*)g;
    float4 v1 = *(const float4*)(g + 4);
    short8 o;
    o[0] = f2b(v0.x); o[1] = f2b(v0.y); o[2] = f2b(v0.z); o[3] = f2b(v0.w);
    o[4] = f2b(v1.x); o[5] = f2b(v1.y); o[6] = f2b(v1.z); o[7] = f2b(v1.w);
    return o;
}

// ---------------------------------------------------------------------------
// C(M x N) = A(M x K) @ B(N x K)^T  -- f32 inputs, bf16 MFMA, f32 accum.
// Tile: TM x 128, BK=32. 256 threads = 4 waves in 2x2; wave = (TM/2) x 64.
// EPI: 0 = store (+bias), 1 = accumulate into C, 2 = attn epilogue
//      (scores[row] += sum_h Va[h]*tanh(acc + qp[b][h] + Uab[h]))
template <int TM, int EPI>
__global__ __launch_bounds__(256) void k_mfma_gemm(
    const float* __restrict__ A, int lda,
    const float* __restrict__ B, int ldb,
    const float* __restrict__ bias,
    float* __restrict__ C, int ldc, int K,
    const float* __restrict__ qp, const float* __restrict__ Uab,
    const float* __restrict__ Va, float* __restrict__ scores) {
    constexpr int WR = TM / 2;      // rows per wave
    constexpr int FM = WR / 16;     // m-fragments per wave
    constexpr int ASLOT = TM / 64;  // A staging slots per thread
    __shared__ short As[TM * 32];
    __shared__ short Bs[128 * 32];

    const int t = threadIdx.x;
    const int l = t & 63;
    const int w = t >> 6;
    const int wm = w >> 1, wn = w & 1;
    const int lr = l & 15, lg = l >> 4;
    const int n0 = blockIdx.x * 128;
    const int r0 = blockIdx.y * TM;

    f32x4 acc[FM][4];
#pragma unroll
    for (int i = 0; i < FM; ++i)
#pragma unroll
        for (int j = 0; j < 4; ++j) {
            f32x4 z = {0.f, 0.f, 0.f, 0.f};
            acc[i][j] = z;
        }

    const int sw = (lg ^ (lr & 3)) << 3;  // swizzled chunk offset for frag reads

    for (int kt = 0; kt < K; kt += 32) {
        // stage A tile (TM x 32) and B tile (128 x 32), converting to bf16.
        // slot = row*4 + chunk; chunk XOR-swizzled by (row&3) to cut conflicts.
#pragma unroll
        for (int i = 0; i < ASLOT; ++i) {
            int s = t + 256 * i;
            int row = s >> 2, ch = s & 3;
            short8 v = ld8(A + (size_t)(r0 + row) * lda + kt + ch * 8);
            *(short8*)&As[row * 32 + ((ch ^ (row & 3)) << 3)] = v;
        }
#pragma unroll
        for (int i = 0; i < 2; ++i) {
            int s = t + 256 * i;
            int row = s >> 2, ch = s & 3;
            short8 v = ld8(B + (size_t)(n0 + row) * ldb + kt + ch * 8);
            *(short8*)&Bs[row * 32 + ((ch ^ (row & 3)) << 3)] = v;
        }
        __syncthreads();

        short8 a[FM], b[4];
#pragma unroll
        for (int i = 0; i < FM; ++i)
            a[i] = *(short8*)&As[(wm * WR + i * 16 + lr) * 32 + sw];
#pragma unroll
        for (int j = 0; j < 4; ++j)
            b[j] = *(short8*)&Bs[(wn * 64 + j * 16 + lr) * 32 + sw];
#pragma unroll
        for (int i = 0; i < FM; ++i)
#pragma unroll
            for (int j = 0; j < 4; ++j)
                acc[i][j] = __builtin_amdgcn_mfma_f32_16x16x32_bf16(a[i], b[j], acc[i][j], 0, 0, 0);
        __syncthreads();
    }

    if constexpr (EPI == 2) {
        // rows of this block = batch blockIdx.y (TM=128 == S)
        const float* qpb = qp + blockIdx.y * 1024;
#pragma unroll
        for (int i = 0; i < FM; ++i)
#pragma unroll
            for (int r = 0; r < 4; ++r) {
                float s = 0.f;
#pragma unroll
                for (int j = 0; j < 4; ++j) {
                    int h = n0 + wn * 64 + j * 16 + lr;
                    s += Va[h] * tanhf(acc[i][j][r] + qpb[h] + Uab[h]);
                }
                s += __shfl_xor(s, 1);
                s += __shfl_xor(s, 2);
                s += __shfl_xor(s, 4);
                s += __shfl_xor(s, 8);
                if (lr == 0)
                    atomicAdd(scores + r0 + wm * WR + i * 16 + lg * 4 + r, s);
            }
    } else {
#pragma unroll
        for (int i = 0; i < FM; ++i)
#pragma unroll
            for (int j = 0; j < 4; ++j)
#pragma unroll
                for (int r = 0; r < 4; ++r) {
                    int R = r0 + wm * WR + i * 16 + lg * 4 + r;
                    int Cc = n0 + wn * 64 + j * 16 + lr;
                    if constexpr (EPI == 1)
                        C[(size_t)R * ldc + Cc] += acc[i][j][r];
                    else
                        C[(size_t)R * ldc + Cc] = acc[i][j][r] + (bias ? bias[Cc] : 0.f);
                }
    }
}

// ---------------------------------------------------------------------------
__global__ void k_gather(const int* __restrict__ idx, const float* __restrict__ emb,
                         float* __restrict__ x) {
    int b = blockIdx.x;
    int row = idx[b];
    const float4* src = (const float4*)(emb + (size_t)row * 1024);
    float4* dst = (float4*)(x + (size_t)b * 2048);
    for (int i = threadIdx.x; i < 256; i += blockDim.x) dst[i] = src[i];
}

__global__ void k_softmax(const float* __restrict__ scores, float* __restrict__ wout) {
    int b = blockIdx.x;
    int s = threadIdx.x;  // 128
    __shared__ float buf[128];
    float v = scores[b * 128 + s];
    buf[s] = v;
    __syncthreads();
    for (int off = 64; off > 0; off >>= 1) {
        if (s < off) buf[s] = fmaxf(buf[s], buf[s + off]);
        __syncthreads();
    }
    float m = buf[0];
    __syncthreads();
    float e = expf(v - m);
    buf[s] = e;
    __syncthreads();
    for (int off = 64; off > 0; off >>= 1) {
        if (s < off) buf[s] += buf[s + off];
        __syncthreads();
    }
    float sum = buf[0];
    wout[b * 128 + s] = e / sum;
}

__global__ void k_context(const float* __restrict__ enc, const float* __restrict__ w,
                          float* __restrict__ x) {
    int b = blockIdx.x;
    int t = threadIdx.x;  // 256
    __shared__ float ws[128];
    if (t < 128) ws[t] = w[b * 128 + t];
    __syncthreads();
    float acc[4] = {0.f, 0.f, 0.f, 0.f};
    for (int s = 0; s < 128; ++s) {
        float wv = ws[s];
        const float* row = enc + ((size_t)b * 128 + s) * 1024;
#pragma unroll
        for (int j = 0; j < 4; ++j) acc[j] += wv * row[t + 256 * j];
    }
#pragma unroll
    for (int j = 0; j < 4; ++j) x[(size_t)b * 2048 + 1024 + t + 256 * j] = acc[j];
}

__global__ void k_lstm(const float* __restrict__ gates, const float* __restrict__ c0,
                       const float* __restrict__ b_ih, const float* __restrict__ b_hh,
                       float* __restrict__ h1, float* __restrict__ c1) {
    int idx = blockIdx.x * blockDim.x + threadIdx.x;  // 65536
    int b = idx >> 10, h = idx & 1023;
    const float* g = gates + (size_t)b * 4096;
    float iv = g[h] + b_ih[h] + b_hh[h];
    float fv = g[1024 + h] + b_ih[1024 + h] + b_hh[1024 + h];
    float gv = g[2048 + h] + b_ih[2048 + h] + b_hh[2048 + h];
    float ov = g[3072 + h] + b_ih[3072 + h] + b_hh[3072 + h];
    float si = 1.f / (1.f + expf(-iv));
    float sf = 1.f / (1.f + expf(-fv));
    float so = 1.f / (1.f + expf(-ov));
    float tg = tanhf(gv);
    float cc = sf * c0[idx] + si * tg;
    float hh = so * tanhf(cc);
    c1[idx] = cc;
    h1[idx] = hh;
}

// ---------------------------------------------------------------------------
extern "C" void kernel_launch(void* const* d_in, const int* in_sizes, int n_in,
                              void* d_out, int out_size, void* d_ws, size_t ws_size,
                              hipStream_t stream) {
    const int* idx = (const int*)d_in[0];
    const float* hidden = (const float*)d_in[1];   // (1,64,1024)
    const float* cell = (const float*)d_in[2];     // (1,64,1024)
    const float* enc = (const float*)d_in[3];      // (64,128,1024)
    const float* emb = (const float*)d_in[4];      // (32000,1024)
    const float* Wa_w = (const float*)d_in[5];     // (1024,1024)
    const float* Wa_b = (const float*)d_in[6];
    const float* Ua_w = (const float*)d_in[7];     // (1024,1024)
    const float* Ua_b = (const float*)d_in[8];
    const float* Va_w = (const float*)d_in[9];     // (1,1024)
    // d_in[10] Va_b unused: softmax shift-invariant
    const float* W_ih = (const float*)d_in[11];    // (4096,2048)
    const float* W_hh = (const float*)d_in[12];    // (4096,1024)
    const float* b_ih = (const float*)d_in[13];
    const float* b_hh = (const float*)d_in[14];
    const float* out_w = (const float*)d_in[15];   // (32000,1024)
    const float* out_b = (const float*)d_in[16];

    float* out = (float*)d_out;
    float* logits = out;                             // 64*32000
    float* h1 = out + 2048000;                       // 64*1024
    float* c1 = out + 2048000 + 65536;               // 64*1024
    float* wts = out + 2048000 + 65536 + 65536;      // 64*128

    float* ws = (float*)d_ws;
    float* qp = ws;                  // 65536
    float* scores = ws + 65536;      // 8192
    float* x = ws + 65536 + 8192;    // 64*2048
    float* gates = x + 131072;       // 64*4096

    hipMemsetAsync(scores, 0, 8192 * sizeof(float), stream);
    k_gather<<<64, 256, 0, stream>>>(idx, emb, x);
    // q_proj = h0 @ Wa^T + Wa_b   (M=64, N=1024, K=1024)
    k_mfma_gemm<64, 0><<<dim3(8, 1), 256, 0, stream>>>(
        hidden, 1024, Wa_w, 1024, Wa_b, qp, 1024, 1024, nullptr, nullptr, nullptr, nullptr);
    // scores: kp = enc @ Ua^T fused tanh/Va reduce  (M=8192, N=1024, K=1024)
    k_mfma_gemm<128, 2><<<dim3(8, 64), 256, 0, stream>>>(
        enc, 1024, Ua_w, 1024, nullptr, nullptr, 0, 1024, qp, Ua_b, Va_w, scores);
    k_softmax<<<64, 128, 0, stream>>>(scores, wts);
    k_context<<<64, 256, 0, stream>>>(enc, wts, x);
    // gates = x @ W_ih^T  then  += h0 @ W_hh^T   (M=64, N=4096)
    k_mfma_gemm<64, 0><<<dim3(32, 1), 256, 0, stream>>>(
        x, 2048, W_ih, 2048, nullptr, gates, 4096, 2048, nullptr, nullptr, nullptr, nullptr);
    k_mfma_gemm<64, 1><<<dim3(32, 1), 256, 0, stream>>>(
        hidden, 1024, W_hh, 1024, nullptr, gates, 4096, 1024, nullptr, nullptr, nullptr, nullptr);
    k_lstm<<<256, 256, 0, stream>>>(gates, cell, b_ih, b_hh, h1, c1);
    // logits = h1 @ out_w^T + out_b   (M=64, N=32000, K=1024)
    k_mfma_gemm<64, 0><<<dim3(250, 1), 256, 0, stream>>>(
        h1, 1024, out_w, 1024, out_b, logits, 32000, 1024, nullptr, nullptr, nullptr, nullptr);
}